// Round 5
// baseline (572.517 us; speedup 1.0000x reference)
//
#include <hip/hip_runtime.h>

#define N_NODES 100000
#define N_EDGES 1600000
#define F 128
#define M_PAD 100032          // 1563 blocks * 64 rows (gemm padding)

#define BUCKET_BITS 9
#define BUCKET_SIZE 512
#define NBUCKETS 196          // ceil(100000/512)
#define BCAP 9216             // padded bucket capacity (mean 8192, +11 sigma)
#define CHUNK_SHIFT 14        // col chunk = col>>14 -> 16384 cols = 4 MiB bf16 slice
#define NCHUNK 7
#define SLOTS (NCHUNK * BUCKET_SIZE)   // 3584 (chunk-major, then row)
#define RS_STRIDE (SLOTS + 1)          // 3585
#define EPB_A 8192
#define ABLOCKS 196

#define SP_BLOCKS 1042        // 4168 waves * 24 rows = 100032 rows covered
#define SP_WAVES 4168
#define ROWS_PW 24

#define AS1 __attribute__((address_space(1)))
#define AS3 __attribute__((address_space(3)))

typedef __attribute__((ext_vector_type(8))) short short8;
typedef __attribute__((ext_vector_type(4))) float f32x4;

__device__ __forceinline__ float bf_lo(unsigned int u) { return __uint_as_float(u << 16); }
__device__ __forceinline__ float bf_hi(unsigned int u) { return __uint_as_float(u & 0xffff0000u); }
__device__ __forceinline__ unsigned short f2bf(float f) {
    unsigned int u = __float_as_uint(f);
    u += 0x7fffu + ((u >> 16) & 1u);   // round-to-nearest-even
    return (unsigned short)(u >> 16);
}
__device__ __forceinline__ void gload_lds16(const void* g, void* l) {
    __builtin_amdgcn_global_load_lds((const AS1 unsigned int*)g, (AS3 unsigned int*)l, 16, 0, 0);
}

// ---------------- CSR build ----------------

__global__ void binit_kernel(int* __restrict__ bucket_cursor) {
    int t = threadIdx.x;
    if (t < NBUCKETS) bucket_cursor[t] = t * BCAP;
}

// pass A: bin edges by bucket (fixed-capacity regions), chunk-reserved writes
__global__ __launch_bounds__(256) void binA_kernel(const int* __restrict__ rows,
                                                   const int* __restrict__ cols,
                                                   const float* __restrict__ vals,
                                                   int* __restrict__ bucket_cursor,
                                                   uint2* __restrict__ stage) {
    __shared__ int hist[NBUCKETS];
    __shared__ int base[NBUCKETS];
    int tid = threadIdx.x;
    int start = blockIdx.x * EPB_A;
    int cnt = min(EPB_A, N_EDGES - start);
    for (int i = tid; i < NBUCKETS; i += 256) hist[i] = 0;
    __syncthreads();
    for (int i = tid; i < cnt; i += 256) atomicAdd(&hist[rows[start + i] >> BUCKET_BITS], 1);
    __syncthreads();
    for (int i = tid; i < NBUCKETS; i += 256) {
        int h = hist[i];
        base[i] = h ? atomicAdd(&bucket_cursor[i], h) : 0;
        hist[i] = 0;
    }
    __syncthreads();
    for (int i = tid; i < cnt; i += 256) {
        int r = rows[start + i];
        int c = cols[start + i];
        unsigned vb = __float_as_uint(vals[start + i]);
        int b = r >> BUCKET_BITS;
        int p = base[b] + atomicAdd(&hist[b], 1);
        stage[p] = make_uint2(((unsigned)(r & (BUCKET_SIZE - 1)) << 17) | (unsigned)c, vb);
    }
}

// pass B: per-bucket sort by (col-chunk, row) -> csr + per-(row,chunk) offsets rs2
__global__ __launch_bounds__(1024) void binB_kernel(const uint2* __restrict__ stage,
                                                    const int* __restrict__ bucket_cursor,
                                                    uint2* __restrict__ csr,
                                                    int* __restrict__ rs2) {
    __shared__ int hist[4096];
    __shared__ int cur[4096];
    __shared__ int tsum[1024];
    int b = blockIdx.x, t = threadIdx.x;
    int s0 = b * BCAP;
    int cnt = bucket_cursor[b] - s0;
#pragma unroll
    for (int i = 0; i < 4; ++i) hist[t * 4 + i] = 0;
    __syncthreads();
    for (int i = t; i < cnt; i += 1024) {
        unsigned xx = stage[s0 + i].x;
        int key = ((int)((xx >> CHUNK_SHIFT) & 7u) << BUCKET_BITS) | (int)(xx >> 17);
        atomicAdd(&hist[key], 1);
    }
    __syncthreads();
    int local = hist[t * 4] + hist[t * 4 + 1] + hist[t * 4 + 2] + hist[t * 4 + 3];
    tsum[t] = local;
    __syncthreads();
    for (int off = 1; off < 1024; off <<= 1) {
        int xv = (t >= off) ? tsum[t - off] : 0;
        __syncthreads();
        tsum[t] += xv;
        __syncthreads();
    }
    int running = s0 + tsum[t] - local;   // global exclusive offset
#pragma unroll
    for (int i = 0; i < 4; ++i) {
        int slot = t * 4 + i;
        if (slot < SLOTS) {
            cur[slot] = running;
            rs2[b * RS_STRIDE + slot] = running;
            running += hist[slot];
        }
    }
    if (t == 1023) rs2[b * RS_STRIDE + SLOTS] = s0 + cnt;   // bucket sentinel
    // zero-fill the padded csr tail so unconditional pipeline loads are safe
    for (int p = s0 + cnt + t; p < s0 + BCAP; p += 1024) csr[p] = make_uint2(0u, 0u);
    __syncthreads();
    for (int i = t; i < cnt; i += 1024) {
        uint2 ee = stage[s0 + i];
        unsigned col = ee.x & 0x1FFFFu;
        int key = ((int)(col >> CHUNK_SHIFT) << BUCKET_BITS) | (int)(ee.x >> 17);
        int p = atomicAdd(&cur[key], 1);
        csr[p] = make_uint2(col, ee.y);
    }
}

// ---------------- W transpose+swizzle pre-kernel ----------------
__global__ __launch_bounds__(256) void wtrans_kernel(const float* __restrict__ W,
                                                     unsigned short* __restrict__ Wt) {
    int t = threadIdx.x;
    int c = t & 127;
    int o0 = (t >> 7) * 8;
    for (int o = o0; o < o0 + 8; ++o) {
        short8 v;
#pragma unroll
        for (int e = 0; e < 8; ++e) v[e] = (short)f2bf(W[(o * 8 + e) * 128 + c]);
        *(short8*)((char*)Wt + c * 256 + ((o * 16) ^ ((c & 7) << 4))) = v;
    }
}

// ---------------- MFMA GEMM: T[node][feat] = A[node][:] @ W ----------------
template <bool IN_BF16>
__global__ __launch_bounds__(256) void mfma_gemm_kernel(const void* __restrict__ Av,
                                                        const unsigned short* __restrict__ Wt,
                                                        unsigned short* __restrict__ T) {
    __shared__ alignas(16) unsigned short wlds[128 * 128];  // 32 KB
    __shared__ alignas(16) unsigned short alds[64 * 128];   // 16 KB
    int tid = threadIdx.x;
    int w = tid >> 6, l = tid & 63;
    int q = l >> 4, c16 = l & 15;
    long r0 = (long)blockIdx.x * 64;

#pragma unroll
    for (int i = 0; i < 8; ++i) {
        int row = w * 32 + i * 4 + q;
        gload_lds16((const char*)Wt + row * 256 + c16 * 16,
                    (char*)wlds + (w * 8192 + i * 1024));
    }
    if constexpr (IN_BF16) {
#pragma unroll
        for (int i = 0; i < 4; ++i) {
            int row = w * 16 + i * 4 + q;
            gload_lds16((const char*)Av + (r0 + row) * 256 + c16 * 16,
                        (char*)alds + (w * 4096 + i * 1024));
        }
    } else {
        const float* X = (const float*)Av;
#pragma unroll
        for (int i = 0; i < 4; ++i) {
            int row = i * 16 + (tid >> 4);
            int oct = tid & 15;
            long rg = r0 + row;
            if (rg > N_NODES - 1) rg = N_NODES - 1;
            const float4* xp = (const float4*)(X + rg * 128 + oct * 8);
            float4 a = xp[0], bb = xp[1];
            short8 v;
            v[0] = (short)f2bf(a.x); v[1] = (short)f2bf(a.y);
            v[2] = (short)f2bf(a.z); v[3] = (short)f2bf(a.w);
            v[4] = (short)f2bf(bb.x); v[5] = (short)f2bf(bb.y);
            v[6] = (short)f2bf(bb.z); v[7] = (short)f2bf(bb.w);
            *(short8*)((char*)alds + row * 256 + ((oct * 16) ^ ((row & 7) << 4))) = v;
        }
    }
    __syncthreads();

    f32x4 acc[8] = {};
    int nrow = w * 16 + c16;
    int nswz = (nrow & 7) << 4;
#pragma unroll
    for (int ks = 0; ks < 4; ++ks) {
        int kb = ks * 64 + q * 16;
        short8 bfrag = *(const short8*)((const char*)alds + nrow * 256 + (kb ^ nswz));
#pragma unroll
        for (int fb = 0; fb < 8; ++fb) {
            int frow = fb * 16 + c16;
            short8 afrag = *(const short8*)((const char*)wlds + frow * 256 +
                                            (kb ^ ((frow & 7) << 4)));
            acc[fb] = __builtin_amdgcn_mfma_f32_16x16x32_bf16(afrag, bfrag, acc[fb], 0, 0, 0);
        }
    }

    long node = r0 + w * 16 + c16;
#pragma unroll
    for (int fb = 0; fb < 8; ++fb) {
        uint2 o;
        o.x = (unsigned)f2bf(acc[fb][0]) | ((unsigned)f2bf(acc[fb][1]) << 16);
        o.y = (unsigned)f2bf(acc[fb][2]) | ((unsigned)f2bf(acc[fb][3]) << 16);
        *(uint2*)((char*)T + node * 256 + fb * 32 + q * 8) = o;
    }
}

// ---------------- Chunked SpMM + fused ReLU ----------------
// Chunk-major (7 slices of <=4 MiB -> per-XCD L2 resident). Each wave owns 24
// strided rows (acc in 48 VGPRs), segments pipelined 8-wide for MLP.
template <bool OUT_BF16>
__global__ __launch_bounds__(256, 4) void spmm2_kernel(const int* __restrict__ rs2,
                                                       const uint2* __restrict__ csr,
                                                       const unsigned int* __restrict__ Tu,
                                                       void* __restrict__ outv) {
    const int wv = blockIdx.x * 4 + (threadIdx.x >> 6);
    const int lane = threadIdx.x & 63;
    float ax[ROWS_PW], ay[ROWS_PW];
#pragma unroll
    for (int k = 0; k < ROWS_PW; ++k) { ax[k] = 0.f; ay[k] = 0.f; }

    for (int c = 0; c < NCHUNK; ++c) {
#pragma unroll
        for (int kg = 0; kg < 3; ++kg) {
            int s[8], e[8];
#pragma unroll
            for (int i = 0; i < 8; ++i) {
                int row = wv + (kg * 8 + i) * SP_WAVES;   // rows >= N have empty segs
                int idx = (row >> BUCKET_BITS) * RS_STRIDE + (c << BUCKET_BITS) +
                          (row & (BUCKET_SIZE - 1));
                s[i] = rs2[idx];
                e[i] = rs2[idx + 1];
            }
            // round 0: first edge of each segment, batch-issued (8 gathers in flight)
            uint2 ed[8];
#pragma unroll
            for (int i = 0; i < 8; ++i) ed[i] = csr[s[i]];   // pad/next-seg reads masked below
            unsigned x[8];
#pragma unroll
            for (int i = 0; i < 8; ++i) x[i] = Tu[(ed[i].x & 0x1FFFFu) * 64 + lane];
            int maxlen = 0;
#pragma unroll
            for (int i = 0; i < 8; ++i) maxlen = max(maxlen, e[i] - s[i]);
#pragma unroll
            for (int i = 0; i < 8; ++i) {
                float v = (s[i] < e[i]) ? __uint_as_float(ed[i].y) : 0.f;
                int k = kg * 8 + i;
                ax[k] = fmaf(v, bf_lo(x[i]), ax[k]);
                ay[k] = fmaf(v, bf_hi(x[i]), ay[k]);
            }
            // remaining rounds, width declines
            for (int r = 1; r < maxlen; ++r) {
                uint2 ed2[8];
                unsigned x2[8];
#pragma unroll
                for (int i = 0; i < 8; ++i) ed2[i] = csr[s[i] + r];
#pragma unroll
                for (int i = 0; i < 8; ++i) x2[i] = Tu[(ed2[i].x & 0x1FFFFu) * 64 + lane];
#pragma unroll
                for (int i = 0; i < 8; ++i) {
                    float v = (s[i] + r < e[i]) ? __uint_as_float(ed2[i].y) : 0.f;
                    int k = kg * 8 + i;
                    ax[k] = fmaf(v, bf_lo(x2[i]), ax[k]);
                    ay[k] = fmaf(v, bf_hi(x2[i]), ay[k]);
                }
            }
        }
    }

#pragma unroll
    for (int k = 0; k < ROWS_PW; ++k) {
        int row = wv + k * SP_WAVES;
        if (k == ROWS_PW - 1 && row >= N_NODES) continue;
        float vx = fmaxf(ax[k], 0.f), vy = fmaxf(ay[k], 0.f);
        if constexpr (OUT_BF16) {
            ((unsigned*)outv)[row * 64 + (lane ^ ((row & 7) << 2))] =
                (unsigned)f2bf(vx) | ((unsigned)f2bf(vy) << 16);
        } else {
            ((float2*)outv)[row * 64 + lane] = make_float2(vx, vy);
        }
    }
}

// ---------------- launch ----------------
extern "C" void kernel_launch(void* const* d_in, const int* in_sizes, int n_in,
                              void* d_out, int out_size, void* d_ws, size_t ws_size,
                              hipStream_t stream) {
    const float* X     = (const float*)d_in[0];
    const float* evals = (const float*)d_in[1];
    const float* W0    = (const float*)d_in[2];
    const float* W1    = (const float*)d_in[3];
    const int* erows   = (const int*)d_in[4];
    const int* ecols   = (const int*)d_in[5];
    float* out = (float*)d_out;

    char* ws = (char*)d_ws;
    size_t off = 0;
    auto carve = [&](size_t bytes) {
        char* p = ws + off;
        off += (bytes + 255) & ~(size_t)255;
        return p;
    };
    unsigned short* T   = (unsigned short*)carve((size_t)M_PAD * F * 2);     // 25.6 MB
    unsigned short* H   = (unsigned short*)carve((size_t)M_PAD * F * 2);     // 25.6 MB
    unsigned short* Wt0 = (unsigned short*)carve(128 * 128 * 2);
    unsigned short* Wt1 = (unsigned short*)carve(128 * 128 * 2);
    uint2* stage        = (uint2*)carve((size_t)NBUCKETS * BCAP * 8);        // 14.5 MB
    uint2* csr          = (uint2*)carve((size_t)NBUCKETS * BCAP * 8);        // 14.5 MB
    int* rs2            = (int*)carve(((size_t)NBUCKETS * RS_STRIDE + 1) * 4); // 2.8 MB
    int* bucket_cursor  = (int*)carve((size_t)NBUCKETS * 4);
    (void)ws_size; (void)in_sizes; (void)n_in; (void)out_size;

    // ---- weight transpose (tiny) ----
    wtrans_kernel<<<1, 256, 0, stream>>>(W0, Wt0);
    wtrans_kernel<<<1, 256, 0, stream>>>(W1, Wt1);

    // ---- CSR build ----
    binit_kernel<<<1, 256, 0, stream>>>(bucket_cursor);
    binA_kernel<<<ABLOCKS, 256, 0, stream>>>(erows, ecols, evals, bucket_cursor, stage);
    binB_kernel<<<NBUCKETS, 1024, 0, stream>>>(stage, bucket_cursor, csr, rs2);

    int gemm_grid = M_PAD / 64;  // 1563

    // ---- layer 0: H = relu(Ahat @ (X @ W0)) ----
    mfma_gemm_kernel<false><<<gemm_grid, 256, 0, stream>>>(X, Wt0, T);
    spmm2_kernel<true><<<SP_BLOCKS, 256, 0, stream>>>(rs2, csr, (const unsigned int*)T, H);

    // ---- layer 1: out = relu(Ahat @ (H @ W1)) ----
    mfma_gemm_kernel<true><<<gemm_grid, 256, 0, stream>>>(H, Wt1, T);
    spmm2_kernel<false><<<SP_BLOCKS, 256, 0, stream>>>(rs2, csr, (const unsigned int*)T, out);
}

// Round 6
// 202.355 us; speedup vs baseline: 2.8293x; 2.8293x over previous
//
#include <hip/hip_runtime.h>

#define N_NODES 100000
#define N_EDGES 1600000
#define F 128
#define M_PAD 100032          // 1563 blocks * 64 rows (gemm padding)

#define BUCKET_BITS 9
#define BUCKET_SIZE 512
#define NBUCKETS 196          // ceil(100000/512)
#define BCAP 9216             // fixed bucket capacity (mean 8192, +11 sigma)
#define EPB_A 8192
#define ABLOCKS 196

#define AS1 __attribute__((address_space(1)))
#define AS3 __attribute__((address_space(3)))

typedef __attribute__((ext_vector_type(8))) short short8;
typedef __attribute__((ext_vector_type(4))) float f32x4;

__device__ __forceinline__ float bf_lo(unsigned int u) { return __uint_as_float(u << 16); }
__device__ __forceinline__ float bf_hi(unsigned int u) { return __uint_as_float(u & 0xffff0000u); }
__device__ __forceinline__ unsigned short f2bf(float f) {
    unsigned int u = __float_as_uint(f);
    u += 0x7fffu + ((u >> 16) & 1u);   // round-to-nearest-even
    return (unsigned short)(u >> 16);
}
__device__ __forceinline__ void gload_lds16(const void* g, void* l) {
    __builtin_amdgcn_global_load_lds((const AS1 unsigned int*)g, (AS3 unsigned int*)l, 16, 0, 0);
}

// ---------------- CSR build (fixed-capacity buckets) ----------------

__global__ void binit_kernel(int* __restrict__ bucket_cursor) {
    int t = threadIdx.x;
    if (t < NBUCKETS) bucket_cursor[t] = t * BCAP;
}

// pass A: bin edges by bucket, chunk-reserved contiguous writes
__global__ __launch_bounds__(256) void binA_kernel(const int* __restrict__ rows,
                                                   const int* __restrict__ cols,
                                                   const float* __restrict__ vals,
                                                   int* __restrict__ bucket_cursor,
                                                   uint2* __restrict__ stage) {
    __shared__ int hist[NBUCKETS];
    __shared__ int base[NBUCKETS];
    int tid = threadIdx.x;
    int start = blockIdx.x * EPB_A;
    int cnt = min(EPB_A, N_EDGES - start);
    for (int i = tid; i < NBUCKETS; i += 256) hist[i] = 0;
    __syncthreads();
    for (int i = tid; i < cnt; i += 256) atomicAdd(&hist[rows[start + i] >> BUCKET_BITS], 1);
    __syncthreads();
    for (int i = tid; i < NBUCKETS; i += 256) {
        int h = hist[i];
        base[i] = h ? atomicAdd(&bucket_cursor[i], h) : 0;
        hist[i] = 0;
    }
    __syncthreads();
    for (int i = tid; i < cnt; i += 256) {
        int r = rows[start + i];
        int c = cols[start + i];
        unsigned vb = __float_as_uint(vals[start + i]);
        int b = r >> BUCKET_BITS;
        int p = base[b] + atomicAdd(&hist[b], 1);
        stage[p] = make_uint2(((unsigned)(r & (BUCKET_SIZE - 1)) << 17) | (unsigned)c, vb);
    }
}

// pass B: per-bucket counting sort by row -> csr (packed col|val) + rowseg{start,end}
__global__ __launch_bounds__(1024) void binB_kernel(const uint2* __restrict__ stage,
                                                    const int* __restrict__ bucket_cursor,
                                                    uint2* __restrict__ csr,
                                                    uint2* __restrict__ rowseg) {
    __shared__ int hist[BUCKET_SIZE];
    __shared__ int scanv[BUCKET_SIZE];
    __shared__ int cur[BUCKET_SIZE];
    int b = blockIdx.x;
    int t = threadIdx.x;
    int s0 = b * BCAP;
    int cnt = bucket_cursor[b] - s0;
    if (t < BUCKET_SIZE) hist[t] = 0;
    __syncthreads();
    for (int i = t; i < cnt; i += 1024) atomicAdd(&hist[stage[s0 + i].x >> 17], 1);
    __syncthreads();
    if (t < BUCKET_SIZE) scanv[t] = hist[t];
    __syncthreads();
    for (int off = 1; off < BUCKET_SIZE; off <<= 1) {
        int x = 0;
        if (t < BUCKET_SIZE && t >= off) x = scanv[t - off];
        __syncthreads();
        if (t < BUCKET_SIZE) scanv[t] += x;
        __syncthreads();
    }
    if (t < BUCKET_SIZE) {
        int st = s0 + scanv[t] - hist[t];   // global exclusive offset
        cur[t] = st;
        int row = (b << BUCKET_BITS) + t;
        if (row < N_NODES) rowseg[row] = make_uint2((unsigned)st, (unsigned)(st + hist[t]));
    }
    __syncthreads();
    for (int i = t; i < cnt; i += 1024) {
        uint2 e = stage[s0 + i];
        int p = atomicAdd(&cur[e.x >> 17], 1);
        csr[p] = make_uint2(e.x & 0x1FFFFu, e.y);
    }
}

// ---------------- W transpose+swizzle pre-kernel ----------------
__global__ __launch_bounds__(256) void wtrans_kernel(const float* __restrict__ W,
                                                     unsigned short* __restrict__ Wt) {
    int t = threadIdx.x;
    int c = t & 127;
    int o0 = (t >> 7) * 8;
    for (int o = o0; o < o0 + 8; ++o) {
        short8 v;
#pragma unroll
        for (int e = 0; e < 8; ++e) v[e] = (short)f2bf(W[(o * 8 + e) * 128 + c]);
        *(short8*)((char*)Wt + c * 256 + ((o * 16) ^ ((c & 7) << 4))) = v;
    }
}

// ---------------- MFMA GEMM: T[node][feat] = A[node][:] @ W ----------------
template <bool IN_BF16>
__global__ __launch_bounds__(256) void mfma_gemm_kernel(const void* __restrict__ Av,
                                                        const unsigned short* __restrict__ Wt,
                                                        unsigned short* __restrict__ T) {
    __shared__ alignas(16) unsigned short wlds[128 * 128];  // 32 KB
    __shared__ alignas(16) unsigned short alds[64 * 128];   // 16 KB
    int tid = threadIdx.x;
    int w = tid >> 6, l = tid & 63;
    int q = l >> 4, c16 = l & 15;
    long r0 = (long)blockIdx.x * 64;

#pragma unroll
    for (int i = 0; i < 8; ++i) {
        int row = w * 32 + i * 4 + q;
        gload_lds16((const char*)Wt + row * 256 + c16 * 16,
                    (char*)wlds + (w * 8192 + i * 1024));
    }
    if constexpr (IN_BF16) {
#pragma unroll
        for (int i = 0; i < 4; ++i) {
            int row = w * 16 + i * 4 + q;
            gload_lds16((const char*)Av + (r0 + row) * 256 + c16 * 16,
                        (char*)alds + (w * 4096 + i * 1024));
        }
    } else {
        const float* X = (const float*)Av;
#pragma unroll
        for (int i = 0; i < 4; ++i) {
            int row = i * 16 + (tid >> 4);
            int oct = tid & 15;
            long rg = r0 + row;
            if (rg > N_NODES - 1) rg = N_NODES - 1;
            const float4* xp = (const float4*)(X + rg * 128 + oct * 8);
            float4 a = xp[0], bb = xp[1];
            short8 v;
            v[0] = (short)f2bf(a.x); v[1] = (short)f2bf(a.y);
            v[2] = (short)f2bf(a.z); v[3] = (short)f2bf(a.w);
            v[4] = (short)f2bf(bb.x); v[5] = (short)f2bf(bb.y);
            v[6] = (short)f2bf(bb.z); v[7] = (short)f2bf(bb.w);
            *(short8*)((char*)alds + row * 256 + ((oct * 16) ^ ((row & 7) << 4))) = v;
        }
    }
    __syncthreads();

    f32x4 acc[8] = {};
    int nrow = w * 16 + c16;
    int nswz = (nrow & 7) << 4;
#pragma unroll
    for (int ks = 0; ks < 4; ++ks) {
        int kb = ks * 64 + q * 16;
        short8 bfrag = *(const short8*)((const char*)alds + nrow * 256 + (kb ^ nswz));
#pragma unroll
        for (int fb = 0; fb < 8; ++fb) {
            int frow = fb * 16 + c16;
            short8 afrag = *(const short8*)((const char*)wlds + frow * 256 +
                                            (kb ^ ((frow & 7) << 4)));
            acc[fb] = __builtin_amdgcn_mfma_f32_16x16x32_bf16(afrag, bfrag, acc[fb], 0, 0, 0);
        }
    }

    long node = r0 + w * 16 + c16;
#pragma unroll
    for (int fb = 0; fb < 8; ++fb) {
        uint2 o;
        o.x = (unsigned)f2bf(acc[fb][0]) | ((unsigned)f2bf(acc[fb][1]) << 16);
        o.y = (unsigned)f2bf(acc[fb][2]) | ((unsigned)f2bf(acc[fb][3]) << 16);
        *(uint2*)((char*)T + node * 256 + fb * 32 + q * 8) = o;
    }
}

// ---------------- SpMM (CSR packed, bf16 gather operand) + fused ReLU ----------------
// One wave per row; lane covers 2 features. 8-wide gather pipeline (8 independent
// VMEM gathers in flight before any FMA consumes). OUT_BF16 writes H pre-swizzled.
template <bool OUT_BF16>
__global__ __launch_bounds__(256) void spmm_relu_kernel(const uint2* __restrict__ rowseg,
                                                        const uint2* __restrict__ csr,
                                                        const unsigned int* __restrict__ Tu,
                                                        void* __restrict__ outv) {
    int wave = threadIdx.x >> 6;
    int lane = threadIdx.x & 63;
    int row = blockIdx.x * 4 + wave;
    uint2 se = rowseg[row];
    int s = (int)se.x;
    int e = (int)se.y;
    float ax = 0.f, ay = 0.f;
    for (int base = s; base < e; base += 64) {
        int cnt = min(64, e - base);
        int col_l = 0; float val_l = 0.f;
        if (lane < cnt) {
            uint2 ed = csr[base + lane];
            col_l = (int)ed.x;
            val_l = __uint_as_float(ed.y);
        }
        int j = 0;
        for (; j + 8 <= cnt; j += 8) {
            int cc[8]; float vv[8]; unsigned xx[8];
#pragma unroll
            for (int i = 0; i < 8; ++i) {
                cc[i] = __shfl(col_l, j + i);
                vv[i] = __shfl(val_l, j + i);
            }
#pragma unroll
            for (int i = 0; i < 8; ++i) xx[i] = Tu[cc[i] * 64 + lane];
#pragma unroll
            for (int i = 0; i < 8; ++i) {
                ax = fmaf(vv[i], bf_lo(xx[i]), ax);
                ay = fmaf(vv[i], bf_hi(xx[i]), ay);
            }
        }
        for (; j + 2 <= cnt; j += 2) {
            int   c0 = __shfl(col_l, j),     c1 = __shfl(col_l, j + 1);
            float v0 = __shfl(val_l, j),     v1 = __shfl(val_l, j + 1);
            unsigned x0 = Tu[c0 * 64 + lane];
            unsigned x1 = Tu[c1 * 64 + lane];
            ax = fmaf(v0, bf_lo(x0), ax); ay = fmaf(v0, bf_hi(x0), ay);
            ax = fmaf(v1, bf_lo(x1), ax); ay = fmaf(v1, bf_hi(x1), ay);
        }
        for (; j < cnt; ++j) {
            int   c = __shfl(col_l, j);
            float v = __shfl(val_l, j);
            unsigned x = Tu[c * 64 + lane];
            ax = fmaf(v, bf_lo(x), ax); ay = fmaf(v, bf_hi(x), ay);
        }
    }
    ax = fmaxf(ax, 0.f);
    ay = fmaxf(ay, 0.f);
    if constexpr (OUT_BF16) {
        unsigned int* o = (unsigned int*)outv;
        o[row * 64 + (lane ^ ((row & 7) << 2))] =
            (unsigned int)f2bf(ax) | ((unsigned int)f2bf(ay) << 16);
    } else {
        float2* o = (float2*)((float*)outv + row * 128 + lane * 2);
        *o = make_float2(ax, ay);
    }
}

// ---------------- launch ----------------
extern "C" void kernel_launch(void* const* d_in, const int* in_sizes, int n_in,
                              void* d_out, int out_size, void* d_ws, size_t ws_size,
                              hipStream_t stream) {
    const float* X     = (const float*)d_in[0];
    const float* evals = (const float*)d_in[1];
    const float* W0    = (const float*)d_in[2];
    const float* W1    = (const float*)d_in[3];
    const int* erows   = (const int*)d_in[4];
    const int* ecols   = (const int*)d_in[5];
    float* out = (float*)d_out;

    char* ws = (char*)d_ws;
    size_t off = 0;
    auto carve = [&](size_t bytes) {
        char* p = ws + off;
        off += (bytes + 255) & ~(size_t)255;
        return p;
    };
    unsigned short* T   = (unsigned short*)carve((size_t)M_PAD * F * 2);   // 25.6 MB
    unsigned short* H   = (unsigned short*)carve((size_t)M_PAD * F * 2);   // 25.6 MB
    unsigned short* Wt0 = (unsigned short*)carve(128 * 128 * 2);
    unsigned short* Wt1 = (unsigned short*)carve(128 * 128 * 2);
    uint2* stage        = (uint2*)carve((size_t)NBUCKETS * BCAP * 8);      // 14.5 MB
    uint2* csr          = (uint2*)carve((size_t)NBUCKETS * BCAP * 8);      // 14.5 MB
    uint2* rowseg       = (uint2*)carve((size_t)N_NODES * 8);              // 0.8 MB
    int* bucket_cursor  = (int*)carve((size_t)NBUCKETS * 4);
    (void)ws_size; (void)in_sizes; (void)n_in; (void)out_size;

    // ---- weight transpose (tiny) ----
    wtrans_kernel<<<1, 256, 0, stream>>>(W0, Wt0);
    wtrans_kernel<<<1, 256, 0, stream>>>(W1, Wt1);

    // ---- CSR build ----
    binit_kernel<<<1, 256, 0, stream>>>(bucket_cursor);
    binA_kernel<<<ABLOCKS, 256, 0, stream>>>(erows, ecols, evals, bucket_cursor, stage);
    binB_kernel<<<NBUCKETS, 1024, 0, stream>>>(stage, bucket_cursor, csr, rowseg);

    int gemm_grid = M_PAD / 64;  // 1563

    // ---- layer 0: H = relu(Ahat @ (X @ W0)) ----
    mfma_gemm_kernel<false><<<gemm_grid, 256, 0, stream>>>(X, Wt0, T);
    spmm_relu_kernel<true><<<N_NODES / 4, 256, 0, stream>>>(rowseg, csr,
                                                            (const unsigned int*)T, H);

    // ---- layer 1: out = relu(Ahat @ (H @ W1)) ----
    mfma_gemm_kernel<true><<<gemm_grid, 256, 0, stream>>>(H, Wt1, T);
    spmm_relu_kernel<false><<<N_NODES / 4, 256, 0, stream>>>(rowseg, csr,
                                                             (const unsigned int*)T, out);
}

// Round 7
// 195.872 us; speedup vs baseline: 2.9229x; 1.0331x over previous
//
#include <hip/hip_runtime.h>

#define N_NODES 100000
#define N_EDGES 1600000
#define F 128
#define M_PAD 100032          // 1563 blocks * 64 rows (gemm padding)

#define BUCKET_BITS 9
#define BUCKET_SIZE 512
#define NBUCKETS 196          // ceil(100000/512)
#define BCAP 9216             // fixed bucket capacity (mean 8192, +11 sigma)
#define EPB_A 8192
#define ABLOCKS 196

#define AS1 __attribute__((address_space(1)))
#define AS3 __attribute__((address_space(3)))

typedef __attribute__((ext_vector_type(8))) short short8;
typedef __attribute__((ext_vector_type(4))) float f32x4;

__device__ __forceinline__ float bf_lo(unsigned int u) { return __uint_as_float(u << 16); }
__device__ __forceinline__ float bf_hi(unsigned int u) { return __uint_as_float(u & 0xffff0000u); }
__device__ __forceinline__ unsigned short f2bf(float f) {
    unsigned int u = __float_as_uint(f);
    u += 0x7fffu + ((u >> 16) & 1u);   // round-to-nearest-even
    return (unsigned short)(u >> 16);
}
__device__ __forceinline__ void gload_lds16(const void* g, void* l) {
    __builtin_amdgcn_global_load_lds((const AS1 unsigned int*)g, (AS3 unsigned int*)l, 16, 0, 0);
}

// ---------------- prep: bucket-cursor init + csr tail pad + both W transposes ----------------
// Wt_swz[c][byte] = bf16(W[k][c]) with byte-in-row swizzled: 16o ^ ((c&7)<<4)
__global__ __launch_bounds__(256) void prep_kernel(const float* __restrict__ W0,
                                                   const float* __restrict__ W1,
                                                   unsigned short* __restrict__ Wt0,
                                                   unsigned short* __restrict__ Wt1,
                                                   int* __restrict__ bucket_cursor,
                                                   uint2* __restrict__ csr_tail) {
    int t = threadIdx.x;
    if (blockIdx.x == 2) {
        if (t < NBUCKETS) bucket_cursor[t] = t * BCAP;
        if (t >= 192 && t < 256) csr_tail[t - 192] = make_uint2(0u, 0u);
        return;
    }
    const float* W = (blockIdx.x == 0) ? W0 : W1;
    unsigned short* Wt = (blockIdx.x == 0) ? Wt0 : Wt1;
    int c = t & 127;
    int o0 = (t >> 7) * 8;
    for (int o = o0; o < o0 + 8; ++o) {
        short8 v;
#pragma unroll
        for (int e = 0; e < 8; ++e) v[e] = (short)f2bf(W[(o * 8 + e) * 128 + c]);
        *(short8*)((char*)Wt + c * 256 + ((o * 16) ^ ((c & 7) << 4))) = v;
    }
}

// ---------------- CSR build (fixed-capacity buckets) ----------------

// pass A: bin edges by bucket, chunk-reserved contiguous writes
__global__ __launch_bounds__(256) void binA_kernel(const int* __restrict__ rows,
                                                   const int* __restrict__ cols,
                                                   const float* __restrict__ vals,
                                                   int* __restrict__ bucket_cursor,
                                                   uint2* __restrict__ stage) {
    __shared__ int hist[NBUCKETS];
    __shared__ int base[NBUCKETS];
    int tid = threadIdx.x;
    int start = blockIdx.x * EPB_A;
    int cnt = min(EPB_A, N_EDGES - start);
    for (int i = tid; i < NBUCKETS; i += 256) hist[i] = 0;
    __syncthreads();
    for (int i = tid; i < cnt; i += 256) atomicAdd(&hist[rows[start + i] >> BUCKET_BITS], 1);
    __syncthreads();
    for (int i = tid; i < NBUCKETS; i += 256) {
        int h = hist[i];
        base[i] = h ? atomicAdd(&bucket_cursor[i], h) : 0;
        hist[i] = 0;
    }
    __syncthreads();
    for (int i = tid; i < cnt; i += 256) {
        int r = rows[start + i];
        int c = cols[start + i];
        unsigned vb = __float_as_uint(vals[start + i]);
        int b = r >> BUCKET_BITS;
        int p = base[b] + atomicAdd(&hist[b], 1);
        stage[p] = make_uint2(((unsigned)(r & (BUCKET_SIZE - 1)) << 17) | (unsigned)c, vb);
    }
}

// pass B: per-bucket counting sort by row -> csr (packed col|val) + rowseg{start,end}.
// Wave-shuffle scan (3 barriers). Zero-fills the bucket's padded csr tail.
__global__ __launch_bounds__(1024) void binB_kernel(const uint2* __restrict__ stage,
                                                    const int* __restrict__ bucket_cursor,
                                                    uint2* __restrict__ csr,
                                                    uint2* __restrict__ rowseg) {
    __shared__ int hist[BUCKET_SIZE];
    __shared__ int scanv[BUCKET_SIZE];
    __shared__ int cur[BUCKET_SIZE];
    __shared__ int wsum[8], woff[8];
    int b = blockIdx.x;
    int t = threadIdx.x;
    int s0 = b * BCAP;
    int cnt = bucket_cursor[b] - s0;
    if (t < BUCKET_SIZE) hist[t] = 0;
    __syncthreads();
    for (int i = t; i < cnt; i += 1024) atomicAdd(&hist[stage[s0 + i].x >> 17], 1);
    __syncthreads();
    int wid = t >> 6, ln = t & 63;
    if (wid < 8) {
        int v = hist[wid * 64 + ln];
#pragma unroll
        for (int d = 1; d < 64; d <<= 1) {
            int u = __shfl_up(v, d);
            if (ln >= d) v += u;
        }
        if (ln == 63) wsum[wid] = v;
        scanv[wid * 64 + ln] = v;       // per-wave inclusive
    }
    __syncthreads();
    if (t == 0) {
        int run = 0;
#pragma unroll
        for (int i = 0; i < 8; ++i) { woff[i] = run; run += wsum[i]; }
    }
    __syncthreads();
    if (t < BUCKET_SIZE) {
        int incl = scanv[t] + woff[t >> 6];            // inclusive scan over 512
        int st = s0 + incl - hist[t];                  // global exclusive offset
        cur[t] = st;
        int row = (b << BUCKET_BITS) + t;
        if (row < N_NODES) rowseg[row] = make_uint2((unsigned)st, (unsigned)(st + hist[t]));
    }
    // zero-fill padded csr tail (spmm reads csr unconditionally, masks by value)
    for (int p = s0 + cnt + t; p < s0 + BCAP; p += 1024) csr[p] = make_uint2(0u, 0u);
    __syncthreads();
    for (int i = t; i < cnt; i += 1024) {
        uint2 e = stage[s0 + i];
        int p = atomicAdd(&cur[e.x >> 17], 1);
        csr[p] = make_uint2(e.x & 0x1FFFFu, e.y);
    }
}

// ---------------- MFMA GEMM: T[node][feat] = A[node][:] @ W ----------------
template <bool IN_BF16>
__global__ __launch_bounds__(256) void mfma_gemm_kernel(const void* __restrict__ Av,
                                                        const unsigned short* __restrict__ Wt,
                                                        unsigned short* __restrict__ T) {
    __shared__ alignas(16) unsigned short wlds[128 * 128];  // 32 KB
    __shared__ alignas(16) unsigned short alds[64 * 128];   // 16 KB
    int tid = threadIdx.x;
    int w = tid >> 6, l = tid & 63;
    int q = l >> 4, c16 = l & 15;
    long r0 = (long)blockIdx.x * 64;

#pragma unroll
    for (int i = 0; i < 8; ++i) {
        int row = w * 32 + i * 4 + q;
        gload_lds16((const char*)Wt + row * 256 + c16 * 16,
                    (char*)wlds + (w * 8192 + i * 1024));
    }
    if constexpr (IN_BF16) {
#pragma unroll
        for (int i = 0; i < 4; ++i) {
            int row = w * 16 + i * 4 + q;
            gload_lds16((const char*)Av + (r0 + row) * 256 + c16 * 16,
                        (char*)alds + (w * 4096 + i * 1024));
        }
    } else {
        const float* X = (const float*)Av;
#pragma unroll
        for (int i = 0; i < 4; ++i) {
            int row = i * 16 + (tid >> 4);
            int oct = tid & 15;
            long rg = r0 + row;
            if (rg > N_NODES - 1) rg = N_NODES - 1;
            const float4* xp = (const float4*)(X + rg * 128 + oct * 8);
            float4 a = xp[0], bb = xp[1];
            short8 v;
            v[0] = (short)f2bf(a.x); v[1] = (short)f2bf(a.y);
            v[2] = (short)f2bf(a.z); v[3] = (short)f2bf(a.w);
            v[4] = (short)f2bf(bb.x); v[5] = (short)f2bf(bb.y);
            v[6] = (short)f2bf(bb.z); v[7] = (short)f2bf(bb.w);
            *(short8*)((char*)alds + row * 256 + ((oct * 16) ^ ((row & 7) << 4))) = v;
        }
    }
    __syncthreads();

    f32x4 acc[8] = {};
    int nrow = w * 16 + c16;
    int nswz = (nrow & 7) << 4;
#pragma unroll
    for (int ks = 0; ks < 4; ++ks) {
        int kb = ks * 64 + q * 16;
        short8 bfrag = *(const short8*)((const char*)alds + nrow * 256 + (kb ^ nswz));
#pragma unroll
        for (int fb = 0; fb < 8; ++fb) {
            int frow = fb * 16 + c16;
            short8 afrag = *(const short8*)((const char*)wlds + frow * 256 +
                                            (kb ^ ((frow & 7) << 4)));
            acc[fb] = __builtin_amdgcn_mfma_f32_16x16x32_bf16(afrag, bfrag, acc[fb], 0, 0, 0);
        }
    }

    long node = r0 + w * 16 + c16;
#pragma unroll
    for (int fb = 0; fb < 8; ++fb) {
        uint2 o;
        o.x = (unsigned)f2bf(acc[fb][0]) | ((unsigned)f2bf(acc[fb][1]) << 16);
        o.y = (unsigned)f2bf(acc[fb][2]) | ((unsigned)f2bf(acc[fb][3]) << 16);
        *(uint2*)((char*)T + node * 256 + fb * 32 + q * 8) = o;
    }
}

// ---------------- SpMM v3 + fused ReLU ----------------
// Half-wave edge pairs: lanes 0-31 / 32-63 process different edges of the same
// row; each lane loads uint2 (4 feats). One VMEM instr = 2 edges. Zero-masked
// overshoot: every row runs full 4-round pipelines, no divergent tails.
template <bool OUT_BF16>
__global__ __launch_bounds__(256) void spmm_relu_kernel(const uint2* __restrict__ rowseg,
                                                        const uint2* __restrict__ csr,
                                                        const uint2* __restrict__ T2,
                                                        void* __restrict__ outv) {
    int wave = threadIdx.x >> 6;
    int lane = threadIdx.x & 63;
    int half = lane >> 5;
    int fl = lane & 31;
    int row = blockIdx.x * 4 + wave;
    uint2 se = rowseg[row];
    int s = (int)se.x, e = (int)se.y;
    float a0 = 0.f, a1 = 0.f, a2 = 0.f, a3 = 0.f;
    for (int base = s; base < e; base += 64) {
        int cnt = min(64, e - base);
        uint2 ed = csr[base + lane];                    // unconditional: pads are zeroed
        int col_l = (lane < cnt) ? (int)ed.x : 0;
        float val_l = (lane < cnt) ? __uint_as_float(ed.y) : 0.f;
        int rounds = (cnt + 7) >> 3;                    // 8 edges per round (4 pairs)
        for (int r = 0; r < rounds; ++r) {
            int j = r * 8;
            int cc[4]; float vv[4]; uint2 xx[4];
#pragma unroll
            for (int i = 0; i < 4; ++i) {
                cc[i] = __shfl(col_l, j + 2 * i + half);
                vv[i] = __shfl(val_l, j + 2 * i + half);
            }
#pragma unroll
            for (int i = 0; i < 4; ++i) xx[i] = T2[cc[i] * 32 + fl];
#pragma unroll
            for (int i = 0; i < 4; ++i) {
                a0 = fmaf(vv[i], bf_lo(xx[i].x), a0);
                a1 = fmaf(vv[i], bf_hi(xx[i].x), a1);
                a2 = fmaf(vv[i], bf_lo(xx[i].y), a2);
                a3 = fmaf(vv[i], bf_hi(xx[i].y), a3);
            }
        }
    }
    a0 += __shfl_xor(a0, 32);
    a1 += __shfl_xor(a1, 32);
    a2 += __shfl_xor(a2, 32);
    a3 += __shfl_xor(a3, 32);
    if (half == 0) {
        a0 = fmaxf(a0, 0.f); a1 = fmaxf(a1, 0.f);
        a2 = fmaxf(a2, 0.f); a3 = fmaxf(a3, 0.f);
        if constexpr (OUT_BF16) {
            uint2 o;
            o.x = (unsigned)f2bf(a0) | ((unsigned)f2bf(a1) << 16);
            o.y = (unsigned)f2bf(a2) | ((unsigned)f2bf(a3) << 16);
            *(uint2*)((char*)outv + (size_t)row * 256 + ((fl * 8) ^ ((row & 7) << 4))) = o;
        } else {
            *(float4*)((float*)outv + (size_t)row * 128 + fl * 4) =
                make_float4(a0, a1, a2, a3);
        }
    }
}

// ---------------- launch ----------------
extern "C" void kernel_launch(void* const* d_in, const int* in_sizes, int n_in,
                              void* d_out, int out_size, void* d_ws, size_t ws_size,
                              hipStream_t stream) {
    const float* X     = (const float*)d_in[0];
    const float* evals = (const float*)d_in[1];
    const float* W0    = (const float*)d_in[2];
    const float* W1    = (const float*)d_in[3];
    const int* erows   = (const int*)d_in[4];
    const int* ecols   = (const int*)d_in[5];
    float* out = (float*)d_out;

    char* ws = (char*)d_ws;
    size_t off = 0;
    auto carve = [&](size_t bytes) {
        char* p = ws + off;
        off += (bytes + 255) & ~(size_t)255;
        return p;
    };
    unsigned short* T   = (unsigned short*)carve((size_t)M_PAD * F * 2);   // 25.6 MB
    unsigned short* H   = (unsigned short*)carve((size_t)M_PAD * F * 2);   // 25.6 MB
    unsigned short* Wt0 = (unsigned short*)carve(128 * 128 * 2);
    unsigned short* Wt1 = (unsigned short*)carve(128 * 128 * 2);
    uint2* stage        = (uint2*)carve((size_t)NBUCKETS * BCAP * 8);      // 14.5 MB
    uint2* csr          = (uint2*)carve(((size_t)NBUCKETS * BCAP + 64) * 8);
    uint2* rowseg       = (uint2*)carve((size_t)N_NODES * 8);              // 0.8 MB
    int* bucket_cursor  = (int*)carve((size_t)NBUCKETS * 4);
    (void)ws_size; (void)in_sizes; (void)n_in; (void)out_size;

    uint2* csr_tail = csr + (size_t)NBUCKETS * BCAP;

    // ---- prep: bucket cursors + csr tail pad + W transposes ----
    prep_kernel<<<3, 256, 0, stream>>>(W0, W1, Wt0, Wt1, bucket_cursor, csr_tail);

    // ---- CSR build ----
    binA_kernel<<<ABLOCKS, 256, 0, stream>>>(erows, ecols, evals, bucket_cursor, stage);
    binB_kernel<<<NBUCKETS, 1024, 0, stream>>>(stage, bucket_cursor, csr, rowseg);

    int gemm_grid = M_PAD / 64;  // 1563

    // ---- layer 0: H = relu(Ahat @ (X @ W0)) ----
    mfma_gemm_kernel<false><<<gemm_grid, 256, 0, stream>>>(X, Wt0, T);
    spmm_relu_kernel<true><<<N_NODES / 4, 256, 0, stream>>>(rowseg, csr,
                                                            (const uint2*)T, H);

    // ---- layer 1: out = relu(Ahat @ (H @ W1)) ----
    mfma_gemm_kernel<true><<<gemm_grid, 256, 0, stream>>>(H, Wt1, T);
    spmm_relu_kernel<false><<<N_NODES / 4, 256, 0, stream>>>(rowseg, csr,
                                                             (const uint2*)T, out);
}